// Round 1
// baseline (351.395 us; speedup 1.0000x reference)
//
#include <hip/hip_runtime.h>

#define HW 512
#define NHALF 256
#define NSEG 254
#define NIMG 48
#define PADN 513

__device__ __forceinline__ unsigned brev9(unsigned x) { return __brev(x) >> 23; }

struct LDS8 {
    float re[8 * PADN];
    float im[8 * PADN];
    float twr[NHALF];
    float twi[NHALF];
};

__device__ __forceinline__ void fill_tw(float* twr, float* twi, int tid) {
    if (tid < NHALF) {
        float ang = -6.2831853071795864769f * (float)tid / 512.0f;
        float s, c;
        sincosf(ang, &s, &c);
        twr[tid] = c;
        twi[tid] = s;
    }
}

// 8 independent 512-point radix-2 DIF FFTs held in LDS (SoA, padded stride).
// Natural-order input, bit-reversed-order result (caller reads at brev9).
__device__ __forceinline__ void fft8_stages(LDS8& L, int tid) {
    for (int sb = 8; sb >= 0; --sb) {
        int s = 1 << sb;
        int t = tid & (s - 1);
        int g = tid >> sb;
        int i = (g << (sb + 1)) + t;
        int ip = i + s;
        int m = t << (8 - sb);
        float wr = L.twr[m], wi = L.twi[m];
#pragma unroll
        for (int c = 0; c < 8; ++c) {
            float* R = L.re + c * PADN;
            float* I = L.im + c * PADN;
            float ar = R[i], ai = I[i], br = R[ip], bi = I[ip];
            float dr = ar - br, di = ai - bi;
            R[i] = ar + br;
            I[i] = ai + bi;
            R[ip] = dr * wr - di * wi;
            I[ip] = dr * wi + di * wr;
        }
        __syncthreads();
    }
}

// Pass 1: FFT along the contiguous axis (y/v) of 8 rows per block. Real input.
__global__ __launch_bounds__(256) void fft_rows_kernel(
    const float* __restrict__ src0, const float* __restrict__ src1,
    float2* __restrict__ dst0, float2* __restrict__ dst1, int img_offset) {
    __shared__ LDS8 L;
    int tid = threadIdx.x;
    int x0 = blockIdx.x * 8;
    int li = blockIdx.y;
    const float* src = blockIdx.z ? src1 : src0;
    float2* dst = blockIdx.z ? dst1 : dst0;
    const float* ibase = src + ((size_t)(img_offset + li) * HW + x0) * HW;
    float2* obase = dst + ((size_t)li * HW + x0) * HW;

    fill_tw(L.twr, L.twi, tid);
    for (int e = tid; e < 8 * HW; e += 256) {
        int y = e & (HW - 1), rx = e >> 9;
        L.re[rx * PADN + y] = ibase[(size_t)rx * HW + y];
        L.im[rx * PADN + y] = 0.0f;
    }
    __syncthreads();
    fft8_stages(L, tid);
    for (int e = tid; e < 8 * HW; e += 256) {
        int k = e & (HW - 1), rx = e >> 9;
        unsigned b = brev9((unsigned)k);
        obase[(size_t)rx * HW + k] = make_float2(L.re[rx * PADN + b], L.im[rx * PADN + b]);
    }
}

// Pass 2: FFT along x for 8 columns per block, in place on the complex buffer.
__global__ __launch_bounds__(256) void fft_cols_kernel(
    float2* __restrict__ dst0, float2* __restrict__ dst1) {
    __shared__ LDS8 L;
    int tid = threadIdx.x;
    int c0 = blockIdx.x * 8;
    int li = blockIdx.y;
    float2* buf = (blockIdx.z ? dst1 : dst0) + (size_t)li * HW * HW;

    fill_tw(L.twr, L.twi, tid);
    for (int e = tid; e < 8 * HW; e += 256) {
        int c = e & 7, x = e >> 3;
        float2 v = buf[(size_t)x * HW + c0 + c];
        L.re[c * PADN + x] = v.x;
        L.im[c * PADN + x] = v.y;
    }
    __syncthreads();
    fft8_stages(L, tid);
    for (int e = tid; e < 8 * HW; e += 256) {
        int c = e & 7, x = e >> 3;
        unsigned b = brev9((unsigned)x);
        buf[(size_t)x * HW + c0 + c] = make_float2(L.re[c * PADN + b], L.im[c * PADN + b]);
    }
}

// Segment boundary detection: segs is sorted ascending, all segments non-empty.
__global__ void seg_bounds_kernel(const int* __restrict__ segs,
                                  int* __restrict__ seg_start, int P) {
    int p = blockIdx.x * 256 + threadIdx.x;
    if (p >= P) return;
    if (p == 0) {
        seg_start[0] = 0;
        seg_start[NSEG] = P;
    } else if (segs[p] != segs[p - 1]) {
        seg_start[segs[p]] = p;
    }
}

// One block per (local img, segment): reduce the contiguous point range.
__global__ __launch_bounds__(256) void gather_kernel(
    const float2* __restrict__ F1, const float2* __restrict__ F2,
    const int* __restrict__ rows, const int* __restrict__ cols,
    const int* __restrict__ seg_start, float4* __restrict__ acc,
    int img_offset) {
    int li = blockIdx.x;
    int s = blockIdx.y;
    int p0 = seg_start[s], p1 = seg_start[s + 1];
    const float2* A = F1 + (size_t)li * HW * HW;
    const float2* B = F2 + (size_t)li * HW * HW;
    float cr = 0.f, ci = 0.f, e1 = 0.f, e2 = 0.f;
    for (int p = p0 + threadIdx.x; p < p1; p += 256) {
        int r = rows[p], c = cols[p];
        float2 a = A[(size_t)r * HW + c];
        float2 b = B[(size_t)r * HW + c];
        cr += a.x * b.x + a.y * b.y;
        ci += a.y * b.x - a.x * b.y;
        e1 += a.x * a.x + a.y * a.y;
        e2 += b.x * b.x + b.y * b.y;
    }
#pragma unroll
    for (int off = 32; off >= 1; off >>= 1) {
        cr += __shfl_down(cr, off, 64);
        ci += __shfl_down(ci, off, 64);
        e1 += __shfl_down(e1, off, 64);
        e2 += __shfl_down(e2, off, 64);
    }
    __shared__ float4 part[4];
    int wid = threadIdx.x >> 6, lane = threadIdx.x & 63;
    if (lane == 0) part[wid] = make_float4(cr, ci, e1, e2);
    __syncthreads();
    if (threadIdx.x == 0) {
        float4 tot = part[0];
        for (int w = 1; w < 4; ++w) {
            tot.x += part[w].x; tot.y += part[w].y;
            tot.z += part[w].z; tot.w += part[w].w;
        }
        acc[(size_t)s * NIMG + (img_offset + li)] = tot;
    }
}

__global__ __launch_bounds__(64) void final_kernel(
    const float4* __restrict__ acc, const float* __restrict__ weight,
    const float* __restrict__ bias, float* __restrict__ out) {
    int img = blockIdx.x;
    int t = threadIdx.x;
    float sum = 0.f;
    for (int s = t; s < NSEG; s += 64) {
        float4 v = acc[(size_t)s * NIMG + img];
        float mag = sqrtf(v.x * v.x + v.y * v.y);
        sum += weight[s + 1] * (mag * rsqrtf(v.z * v.w));
    }
#pragma unroll
    for (int off = 32; off >= 1; off >>= 1) sum += __shfl_down(sum, off, 64);
    if (t == 0) out[img] = sum + weight[0] + bias[0];
}

extern "C" void kernel_launch(void* const* d_in, const int* in_sizes, int n_in,
                              void* d_out, int out_size, void* d_ws, size_t ws_size,
                              hipStream_t stream) {
    const float* input  = (const float*)d_in[0];
    const float* target = (const float*)d_in[1];
    const int* rows     = (const int*)d_in[2];
    const int* cols     = (const int*)d_in[3];
    const int* segs     = (const int*)d_in[4];
    const float* weight = (const float*)d_in[5];
    const float* bias   = (const float*)d_in[6];
    float* out = (float*)d_out;
    int P = in_sizes[2];

    char* ws = (char*)d_ws;
    float4* acc = (float4*)ws;                                   // NSEG*NIMG float4
    size_t accBytes = (size_t)NSEG * NIMG * sizeof(float4);      // 195072 B
    int* seg_start = (int*)(ws + accBytes);                      // 256 ints
    size_t off = accBytes + 256 * sizeof(int);
    off = (off + 255) & ~(size_t)255;
    size_t remain = (ws_size > off) ? (ws_size - off) : 0;
    size_t perPair = 2ull * HW * HW * sizeof(float2);            // 4 MB (F1+F2 per pair)
    const int chs[10] = {48, 24, 16, 12, 8, 6, 4, 3, 2, 1};
    int CH = 1;
    for (int i = 0; i < 10; ++i)
        if ((size_t)chs[i] * perPair <= remain) { CH = chs[i]; break; }
    float2* F1 = (float2*)(ws + off);
    float2* F2 = F1 + (size_t)CH * HW * HW;

    seg_bounds_kernel<<<(P + 255) / 256, 256, 0, stream>>>(segs, seg_start, P);

    for (int k = 0; k < NIMG; k += CH) {
        dim3 g1(HW / 8, CH, 2);
        fft_rows_kernel<<<g1, 256, 0, stream>>>(input, target, F1, F2, k);
        dim3 g2(HW / 8, CH, 2);
        fft_cols_kernel<<<g2, 256, 0, stream>>>(F1, F2);
        dim3 g3(CH, NSEG, 1);
        gather_kernel<<<g3, 256, 0, stream>>>(F1, F2, rows, cols, seg_start, acc, k);
    }
    final_kernel<<<NIMG, 64, 0, stream>>>(acc, weight, bias, out);
}

// Round 2
// 161.083 us; speedup vs baseline: 2.1814x; 2.1814x over previous
//
#include <hip/hip_runtime.h>

#define HW 512
#define NSEG 254
#define NIMG 48
#define CPAD 516  // channel stride in floats: 512 data + 4-bank skew per channel

__device__ __forceinline__ unsigned brev9(unsigned x) { return __brev(x) >> 23; }
// Bank swizzle: inject address bits 5,6,7 into bank-field bits {3,4},{1,2},{0}.
// Bijective on [0,512). Gives <=2-way bank aliasing for every FFT stage's
// quad access pattern AND the bit-reversed output read (derived per stage).
__device__ __forceinline__ int swz(int i) {
    return i ^ ((i >> 2) & 0x18) ^ ((i >> 4) & 6) ^ ((i >> 7) & 1);
}

struct LDS8 {
    float re[8 * CPAD];
    float im[8 * CPAD];
    float twr[512];
    float twi[512];
};

__device__ __forceinline__ void fill_tw(LDS8& L, int tid) {
#pragma unroll
    for (int h = 0; h < 2; ++h) {
        int m = tid + h * 256;
        float s, c;
        sincosf(-6.2831853071795864769f * (float)m / 512.0f, &s, &c);
        L.twr[m] = c;
        L.twi[m] = s;
    }
}

// 8 independent 512-pt FFTs in LDS. Natural-order in, bit-reversed out.
// Stage plan: radix-2 (dist 256), then 4 fused radix-4 stages (sb=7,5,3,1).
// Thread t handles quad position (t&127) for 4 channels ((t>>7)*4 ..+3).
__device__ __forceinline__ void fft8(LDS8& L, int tid) {
    int qpos = tid & 127;
    int cbase = (tid >> 7) * 4;
    {  // radix-2 stage, distance 256; two butterflies per thread per channel
        float wr0 = L.twr[qpos], wi0 = L.twi[qpos];
        float wr1 = L.twr[qpos + 128], wi1 = L.twi[qpos + 128];
        int a0 = swz(qpos), b0 = swz(qpos + 256);
        int a1 = swz(qpos + 128), b1 = swz(qpos + 384);
#pragma unroll
        for (int cc = 0; cc < 4; ++cc) {
            float* R = L.re + (cbase + cc) * CPAD;
            float* I = L.im + (cbase + cc) * CPAD;
            {
                float ar = R[a0], ai = I[a0], br = R[b0], bi = I[b0];
                float dr = ar - br, di = ai - bi;
                R[a0] = ar + br; I[a0] = ai + bi;
                R[b0] = dr * wr0 - di * wi0;
                I[b0] = dr * wi0 + di * wr0;
            }
            {
                float ar = R[a1], ai = I[a1], br = R[b1], bi = I[b1];
                float dr = ar - br, di = ai - bi;
                R[a1] = ar + br; I[a1] = ai + bi;
                R[b1] = dr * wr1 - di * wi1;
                I[b1] = dr * wi1 + di * wr1;
            }
        }
    }
    __syncthreads();
#pragma unroll
    for (int sb = 7; sb >= 1; sb -= 2) {  // fused radix-4 (radix-2 stages sb, sb-1)
        int s2 = 1 << (sb - 1);
        int t = qpos & (s2 - 1);
        int g = qpos >> (sb - 1);
        int i = (g << (sb + 1)) + t;
        float w1r = L.twr[t << (8 - sb)], w1i = L.twi[t << (8 - sb)];
        float w2r = L.twr[t << (9 - sb)], w2i = L.twi[t << (9 - sb)];
        float w3r = L.twr[(3 * t) << (8 - sb)], w3i = L.twi[(3 * t) << (8 - sb)];
        int a0 = swz(i), a1 = swz(i + s2), a2 = swz(i + 2 * s2), a3 = swz(i + 3 * s2);
#pragma unroll
        for (int cc = 0; cc < 4; ++cc) {
            float* R = L.re + (cbase + cc) * CPAD;
            float* I = L.im + (cbase + cc) * CPAD;
            float x0r = R[a0], x0i = I[a0];
            float x1r = R[a1], x1i = I[a1];
            float x2r = R[a2], x2i = I[a2];
            float x3r = R[a3], x3i = I[a3];
            float u0r = x0r + x2r, u0i = x0i + x2i;
            float u2r = x0r - x2r, u2i = x0i - x2i;
            float u1r = x1r + x3r, u1i = x1i + x3i;
            float u3r = x1i - x3i, u3i = x3r - x1r;  // -i*(x1-x3)
            R[a0] = u0r + u1r; I[a0] = u0i + u1i;
            float t1r = u0r - u1r, t1i = u0i - u1i;
            R[a1] = t1r * w2r - t1i * w2i; I[a1] = t1r * w2i + t1i * w2r;
            float t2r = u2r + u3r, t2i = u2i + u3i;
            R[a2] = t2r * w1r - t2i * w1i; I[a2] = t2r * w1i + t2i * w1r;
            float t3r = u2r - u3r, t3i = u2i - u3i;
            R[a3] = t3r * w3r - t3i * w3i; I[a3] = t3r * w3i + t3i * w3r;
        }
        __syncthreads();
    }
}

// Pass 1: FFT along y of 8 rows per block; re = input, im = target (packed).
__global__ __launch_bounds__(256) void fft_rows_kernel(
    const float* __restrict__ input, const float* __restrict__ target,
    float2* __restrict__ F, int img_offset) {
    __shared__ LDS8 L;
    int tid = threadIdx.x;
    int x0 = blockIdx.x * 8;
    int li = blockIdx.y;
    const float* ib = input + ((size_t)(img_offset + li) * HW + x0) * HW;
    const float* tb = target + ((size_t)(img_offset + li) * HW + x0) * HW;
    float2* ob = F + ((size_t)li * HW + x0) * HW;

    fill_tw(L, tid);
    for (int e = tid; e < 8 * HW; e += 256) {
        int y = e & (HW - 1), rx = e >> 9;
        int a = rx * CPAD + swz(y);
        L.re[a] = ib[(size_t)rx * HW + y];
        L.im[a] = tb[(size_t)rx * HW + y];
    }
    __syncthreads();
    fft8(L, tid);
    for (int e = tid; e < 8 * HW; e += 256) {
        int k = e & (HW - 1), rx = e >> 9;
        int a = rx * CPAD + swz((int)brev9((unsigned)k));
        ob[(size_t)rx * HW + k] = make_float2(L.re[a], L.im[a]);
    }
}

// Pass 2: FFT along x for 8 columns per block, in place.
__global__ __launch_bounds__(256) void fft_cols_kernel(float2* __restrict__ F) {
    __shared__ LDS8 L;
    int tid = threadIdx.x;
    int c0 = blockIdx.x * 8;
    int li = blockIdx.y;
    float2* buf = F + (size_t)li * HW * HW;

    fill_tw(L, tid);
    for (int e = tid; e < 8 * HW; e += 256) {
        int c = e & 7, x = e >> 3;
        float2 v = buf[(size_t)x * HW + c0 + c];
        int a = c * CPAD + swz(x);
        L.re[a] = v.x;
        L.im[a] = v.y;
    }
    __syncthreads();
    fft8(L, tid);
    for (int e = tid; e < 8 * HW; e += 256) {
        int c = e & 7, x = e >> 3;
        int a = c * CPAD + swz((int)brev9((unsigned)x));
        buf[(size_t)x * HW + c0 + c] = make_float2(L.re[a], L.im[a]);
    }
}

__global__ void seg_bounds_kernel(const int* __restrict__ segs,
                                  int* __restrict__ seg_start, int P) {
    int p = blockIdx.x * 256 + threadIdx.x;
    if (p >= P) return;
    if (p == 0) {
        seg_start[0] = 0;
        seg_start[NSEG] = P;
    } else if (segs[p] != segs[p - 1]) {
        seg_start[segs[p]] = p;
    }
}

// One wave per (local img, segment). Reconstruct both spectra from the packed
// FFT via conjugate symmetry: u=F[r,c], v=F[-r,-c];
//   a=2*F_in=(u.x+v.x, u.y-v.y), b=2*F_tg=(u.y+v.y, v.x-u.x).
// The uniform x2 scale cancels in |cross|/sqrt(e1*e2).
__global__ __launch_bounds__(64) void gather_kernel(
    const float2* __restrict__ F, const int* __restrict__ rows,
    const int* __restrict__ cols, const int* __restrict__ seg_start,
    float4* __restrict__ acc, int img_offset) {
    int li = blockIdx.x;
    int s = blockIdx.y;
    int p0 = seg_start[s], p1 = seg_start[s + 1];
    const float2* A = F + (size_t)li * HW * HW;
    float cr = 0.f, ci = 0.f, e1 = 0.f, e2 = 0.f;
    for (int p = p0 + threadIdx.x; p < p1; p += 64) {
        int r = rows[p], c = cols[p];  // r,c in [3,509] -> HW-r, HW-c valid
        float2 u = A[(size_t)r * HW + c];
        float2 v = A[(size_t)(HW - r) * HW + (HW - c)];
        float ar = u.x + v.x, ai = u.y - v.y;
        float br = u.y + v.y, bi = v.x - u.x;
        cr += ar * br + ai * bi;
        ci += ai * br - ar * bi;
        e1 += ar * ar + ai * ai;
        e2 += br * br + bi * bi;
    }
#pragma unroll
    for (int off = 32; off >= 1; off >>= 1) {
        cr += __shfl_down(cr, off, 64);
        ci += __shfl_down(ci, off, 64);
        e1 += __shfl_down(e1, off, 64);
        e2 += __shfl_down(e2, off, 64);
    }
    if (threadIdx.x == 0)
        acc[(size_t)s * NIMG + (img_offset + li)] = make_float4(cr, ci, e1, e2);
}

__global__ __launch_bounds__(64) void final_kernel(
    const float4* __restrict__ acc, const float* __restrict__ weight,
    const float* __restrict__ bias, float* __restrict__ out) {
    int img = blockIdx.x;
    int t = threadIdx.x;
    float sum = 0.f;
    for (int s = t; s < NSEG; s += 64) {
        float4 v = acc[(size_t)s * NIMG + img];
        float mag = sqrtf(v.x * v.x + v.y * v.y);
        sum += weight[s + 1] * (mag * rsqrtf(v.z * v.w));
    }
#pragma unroll
    for (int off = 32; off >= 1; off >>= 1) sum += __shfl_down(sum, off, 64);
    if (t == 0) out[img] = sum + weight[0] + bias[0];
}

extern "C" void kernel_launch(void* const* d_in, const int* in_sizes, int n_in,
                              void* d_out, int out_size, void* d_ws, size_t ws_size,
                              hipStream_t stream) {
    const float* input  = (const float*)d_in[0];
    const float* target = (const float*)d_in[1];
    const int* rows     = (const int*)d_in[2];
    const int* cols     = (const int*)d_in[3];
    const int* segs     = (const int*)d_in[4];
    const float* weight = (const float*)d_in[5];
    const float* bias   = (const float*)d_in[6];
    float* out = (float*)d_out;
    int P = in_sizes[2];

    char* ws = (char*)d_ws;
    float4* acc = (float4*)ws;                               // NSEG*NIMG float4
    size_t accBytes = (size_t)NSEG * NIMG * sizeof(float4);  // 195072 B
    int* seg_start = (int*)(ws + accBytes);                  // 256 ints
    size_t off = accBytes + 256 * sizeof(int);
    off = (off + 255) & ~(size_t)255;
    size_t remain = (ws_size > off) ? (ws_size - off) : 0;
    size_t perImg = (size_t)HW * HW * sizeof(float2);        // 2 MB per image
    const int chs[10] = {48, 24, 16, 12, 8, 6, 4, 3, 2, 1};
    int CH = 1;
    for (int i = 0; i < 10; ++i)
        if ((size_t)chs[i] * perImg <= remain) { CH = chs[i]; break; }
    float2* F = (float2*)(ws + off);

    seg_bounds_kernel<<<(P + 255) / 256, 256, 0, stream>>>(segs, seg_start, P);

    for (int k = 0; k < NIMG; k += CH) {
        dim3 g1(HW / 8, CH);
        fft_rows_kernel<<<g1, 256, 0, stream>>>(input, target, F, k);
        dim3 g2(HW / 8, CH);
        fft_cols_kernel<<<g2, 256, 0, stream>>>(F);
        dim3 g3(CH, NSEG);
        gather_kernel<<<g3, 64, 0, stream>>>(F, rows, cols, seg_start, acc, k);
    }
    final_kernel<<<NIMG, 64, 0, stream>>>(acc, weight, bias, out);
}

// Round 3
// 137.002 us; speedup vs baseline: 2.5649x; 1.1758x over previous
//
#include <hip/hip_runtime.h>

#define HW 512
#define IMGPIX (HW * HW)
#define NSEG 254
#define NIMG 48
#define SLICE 516  // per-wave float2 LDS slice stride (512 data + 4 skew)

// ---------------- 8-point DFT in registers (DIF, natural-order outputs) ----
__device__ __forceinline__ void dft8(float xr[8], float xi[8]) {
    const float C = 0.70710678118654752440f;
    float b0r = xr[0] + xr[4], b0i = xi[0] + xi[4];
    float b1r = xr[1] + xr[5], b1i = xi[1] + xi[5];
    float b2r = xr[2] + xr[6], b2i = xi[2] + xi[6];
    float b3r = xr[3] + xr[7], b3i = xi[3] + xi[7];
    float d4r = xr[0] - xr[4], d4i = xi[0] - xi[4];
    float d5r = xr[1] - xr[5], d5i = xi[1] - xi[5];
    float d6r = xr[2] - xr[6], d6i = xi[2] - xi[6];
    float d7r = xr[3] - xr[7], d7i = xi[3] - xi[7];
    float b4r = d4r, b4i = d4i;
    float b5r = C * (d5r + d5i), b5i = C * (d5i - d5r);   // * W8^1
    float b6r = d6i, b6i = -d6r;                          // * -i
    float b7r = C * (d7i - d7r), b7i = -C * (d7r + d7i);  // * W8^3
    float c0r = b0r + b2r, c0i = b0i + b2i;
    float c1r = b1r + b3r, c1i = b1i + b3i;
    float e2r = b0r - b2r, e2i = b0i - b2i;
    float e3r = b1r - b3r, e3i = b1i - b3i;
    float c3r = e3i, c3i = -e3r;                          // * -i
    float c4r = b4r + b6r, c4i = b4i + b6i;
    float c5r = b5r + b7r, c5i = b5i + b7i;
    float e6r = b4r - b6r, e6i = b4i - b6i;
    float e7r = b5r - b7r, e7i = b5i - b7i;
    float c7r = e7i, c7i = -e7r;                          // * -i
    xr[0] = c0r + c1r; xi[0] = c0i + c1i;
    xr[4] = c0r - c1r; xi[4] = c0i - c1i;
    xr[2] = e2r + c3r; xi[2] = e2i + c3i;
    xr[6] = e2r - c3r; xi[6] = e2i - c3i;
    xr[1] = c4r + c5r; xi[1] = c4i + c5i;
    xr[5] = c4r - c5r; xi[5] = c4i - c5i;
    xr[3] = e6r + c7r; xi[3] = e6i + c7i;
    xr[7] = e6r - c7r; xi[7] = e6i - c7i;
}

// Multiply slot k (k=1..7) by w^k, w = e^{i*ang}.
__device__ __forceinline__ void tw_apply(float xr[8], float xi[8], float ang) {
    float s, c;
    sincosf(ang, &s, &c);
    float pr = c, pi = s;
#pragma unroll
    for (int k = 1; k < 8; ++k) {
        float tr = xr[k] * pr - xi[k] * pi;
        float ti = xr[k] * pi + xi[k] * pr;
        xr[k] = tr; xi[k] = ti;
        if (k < 7) { float nr = pr * c - pi * s; pi = pr * s + pi * c; pr = nr; }
    }
}

// Per-wave 512-pt FFT. In: slot j holds point n = j*64 + l (natural order).
// Out: lane (k1=l>>3, j2=l&7), slot j3 holds X[k1 + 8*j2 + 64*j3].
// ex: this wave's private float2 buffer (>=512 elems). No block barriers.
// XOR swizzles keep every b64 exchange at the 4-way floor (conflict-free).
__device__ __forceinline__ void wave_fft512(float xr[8], float xi[8],
                                            float2* ex, int l) {
    const float TWO_PI = 6.28318530717958647692f;
    dft8(xr, xi);
    tw_apply(xr, xi, -TWO_PI * (float)l * (1.0f / 512.0f));
#pragma unroll
    for (int k1 = 0; k1 < 8; ++k1)
        ex[k1 * 64 + (l ^ (k1 << 3))] = make_float2(xr[k1], xi[k1]);
    asm volatile("s_waitcnt lgkmcnt(0)" ::: "memory");
    int hi = l >> 3, lo = l & 7;
#pragma unroll
    for (int m1 = 0; m1 < 8; ++m1) {
        float2 v = ex[hi * 64 + ((m1 ^ hi) << 3) + lo];
        xr[m1] = v.x; xi[m1] = v.y;
    }
    dft8(xr, xi);
    tw_apply(xr, xi, -TWO_PI * (float)lo * (1.0f / 64.0f));
#pragma unroll
    for (int j2 = 0; j2 < 8; ++j2)
        ex[hi * 64 + ((j2 ^ hi) << 3) + (lo ^ hi)] = make_float2(xr[j2], xi[j2]);
    asm volatile("s_waitcnt lgkmcnt(0)" ::: "memory");
#pragma unroll
    for (int m2 = 0; m2 < 8; ++m2) {
        float2 v = ex[hi * 64 + ((lo ^ hi) << 3) + (m2 ^ hi)];
        xr[m2] = v.x; xi[m2] = v.y;
    }
    dft8(xr, xi);
}

// Pass 1: FFT along contiguous axis; one row-FFT per wave, 4 waves/block.
// re = input, im = target (real-pair packing). No __syncthreads at all.
__global__ __launch_bounds__(256) void fft_rows_kernel(
    const float* __restrict__ input, const float* __restrict__ target,
    float2* __restrict__ F, int img_offset) {
    __shared__ float2 ex[4 * SLICE];
    int tid = threadIdx.x, w = tid >> 6, l = tid & 63;
    int x = blockIdx.x * 4 + w;
    int li = blockIdx.y;
    const float* ib = input + (size_t)(img_offset + li) * IMGPIX + (size_t)x * HW;
    const float* tb = target + (size_t)(img_offset + li) * IMGPIX + (size_t)x * HW;
    float xr[8], xi[8];
#pragma unroll
    for (int j = 0; j < 8; ++j) {
        xr[j] = ib[j * 64 + l];
        xi[j] = tb[j * 64 + l];
    }
    wave_fft512(xr, xi, ex + w * SLICE, l);
    float2* ob = F + ((size_t)li * HW + x) * HW;
    int hi = l >> 3, lo = l & 7;
#pragma unroll
    for (int j3 = 0; j3 < 8; ++j3)
        ob[hi + (lo << 3) + (j3 << 6)] = make_float2(xr[j3], xi[j3]);
}

// Pass 2: FFT along x for 8 columns/block (one per wave), tile-staged for
// coalesced global access. Two barriers total.
__global__ __launch_bounds__(512) void fft_cols_kernel(float2* __restrict__ F) {
    __shared__ float2 tile[8 * SLICE];
    int tid = threadIdx.x, w = tid >> 6, l = tid & 63;
    int c0 = blockIdx.x * 8;
    float2* buf = F + (size_t)blockIdx.y * IMGPIX;
#pragma unroll
    for (int it = 0; it < 8; ++it) {
        int e = it * 512 + tid;
        int xx = e >> 3, cc = e & 7;
        tile[cc * SLICE + xx] = buf[(size_t)xx * HW + c0 + cc];
    }
    __syncthreads();
    float xr[8], xi[8];
#pragma unroll
    for (int j = 0; j < 8; ++j) {
        float2 v = tile[w * SLICE + j * 64 + l];
        xr[j] = v.x; xi[j] = v.y;
    }
    wave_fft512(xr, xi, tile + w * SLICE, l);  // wave-private slice reuse
    int hi = l >> 3, lo = l & 7;
#pragma unroll
    for (int j3 = 0; j3 < 8; ++j3)
        tile[w * SLICE + hi + (lo << 3) + (j3 << 6)] = make_float2(xr[j3], xi[j3]);
    __syncthreads();
#pragma unroll
    for (int it = 0; it < 8; ++it) {
        int e = it * 512 + tid;
        int kk = e >> 3, cc = e & 7;
        buf[(size_t)kk * HW + c0 + cc] = tile[cc * SLICE + kk];
    }
}

__global__ void seg_bounds_kernel(const int* __restrict__ segs,
                                  int* __restrict__ seg_start, int P) {
    int p = blockIdx.x * 256 + threadIdx.x;
    if (p >= P) return;
    if (p == 0) {
        seg_start[0] = 0;
        seg_start[NSEG] = P;
    } else if (segs[p] != segs[p - 1]) {
        seg_start[segs[p]] = p;
    }
}

// One wave per (local img, segment). Packed-FFT split via conj symmetry:
// u=F[r,c], v=F[-r,-c]; a=(u.x+v.x, u.y-v.y), b=(u.y+v.y, v.x-u.x);
// uniform 2x scale cancels in |cross|/sqrt(e1*e2).
__global__ __launch_bounds__(64) void gather_kernel(
    const float2* __restrict__ F, const int* __restrict__ rows,
    const int* __restrict__ cols, const int* __restrict__ seg_start,
    float4* __restrict__ acc, int img_offset) {
    int li = blockIdx.x;
    int s = blockIdx.y;
    int p0 = seg_start[s], p1 = seg_start[s + 1];
    const float2* A = F + (size_t)li * IMGPIX;
    float cr = 0.f, ci = 0.f, e1 = 0.f, e2 = 0.f;
    for (int p = p0 + threadIdx.x; p < p1; p += 64) {
        int r = rows[p], c = cols[p];
        float2 u = A[(size_t)r * HW + c];
        float2 v = A[(size_t)(HW - r) * HW + (HW - c)];
        float ar = u.x + v.x, ai = u.y - v.y;
        float br = u.y + v.y, bi = v.x - u.x;
        cr += ar * br + ai * bi;
        ci += ai * br - ar * bi;
        e1 += ar * ar + ai * ai;
        e2 += br * br + bi * bi;
    }
#pragma unroll
    for (int off = 32; off >= 1; off >>= 1) {
        cr += __shfl_down(cr, off, 64);
        ci += __shfl_down(ci, off, 64);
        e1 += __shfl_down(e1, off, 64);
        e2 += __shfl_down(e2, off, 64);
    }
    if (threadIdx.x == 0)
        acc[(size_t)s * NIMG + (img_offset + li)] = make_float4(cr, ci, e1, e2);
}

__global__ __launch_bounds__(64) void final_kernel(
    const float4* __restrict__ acc, const float* __restrict__ weight,
    const float* __restrict__ bias, float* __restrict__ out) {
    int img = blockIdx.x;
    int t = threadIdx.x;
    float sum = 0.f;
    for (int s = t; s < NSEG; s += 64) {
        float4 v = acc[(size_t)s * NIMG + img];
        float mag = sqrtf(v.x * v.x + v.y * v.y);
        sum += weight[s + 1] * (mag * rsqrtf(v.z * v.w));
    }
#pragma unroll
    for (int off = 32; off >= 1; off >>= 1) sum += __shfl_down(sum, off, 64);
    if (t == 0) out[img] = sum + weight[0] + bias[0];
}

extern "C" void kernel_launch(void* const* d_in, const int* in_sizes, int n_in,
                              void* d_out, int out_size, void* d_ws, size_t ws_size,
                              hipStream_t stream) {
    const float* input  = (const float*)d_in[0];
    const float* target = (const float*)d_in[1];
    const int* rows     = (const int*)d_in[2];
    const int* cols     = (const int*)d_in[3];
    const int* segs     = (const int*)d_in[4];
    const float* weight = (const float*)d_in[5];
    const float* bias   = (const float*)d_in[6];
    float* out = (float*)d_out;
    int P = in_sizes[2];

    char* ws = (char*)d_ws;
    float4* acc = (float4*)ws;                               // NSEG*NIMG float4
    size_t accBytes = (size_t)NSEG * NIMG * sizeof(float4);  // 195072 B
    int* seg_start = (int*)(ws + accBytes);                  // 256 ints
    size_t off = accBytes + 256 * sizeof(int);
    off = (off + 255) & ~(size_t)255;
    size_t remain = (ws_size > off) ? (ws_size - off) : 0;
    size_t perImg = (size_t)IMGPIX * sizeof(float2);         // 2 MB per image
    const int chs[10] = {48, 24, 16, 12, 8, 6, 4, 3, 2, 1};
    int CH = 1;
    for (int i = 0; i < 10; ++i)
        if ((size_t)chs[i] * perImg <= remain) { CH = chs[i]; break; }
    float2* F = (float2*)(ws + off);

    seg_bounds_kernel<<<(P + 255) / 256, 256, 0, stream>>>(segs, seg_start, P);

    for (int k = 0; k < NIMG; k += CH) {
        dim3 g1(HW / 4, CH);
        fft_rows_kernel<<<g1, 256, 0, stream>>>(input, target, F, k);
        dim3 g2(HW / 8, CH);
        fft_cols_kernel<<<g2, 512, 0, stream>>>(F);
        dim3 g3(CH, NSEG);
        gather_kernel<<<g3, 64, 0, stream>>>(F, rows, cols, seg_start, acc, k);
    }
    final_kernel<<<NIMG, 64, 0, stream>>>(acc, weight, bias, out);
}